// Round 18
// baseline (41.405 us; speedup 1.0000x reference)
//
#include <hip/hip_runtime.h>
#include <hip/hip_bf16.h>
#include <stdint.h>

// Quanvolution + linear(784->10) + log_softmax via MFMA, B=65536, fp32 in/out.
// R17: CONTIGUOUS staging test. Each block's 16-row x-tile (49KB) is
// contiguous in memory; stage it to LDS with 49 x global_load_lds(16B)
// instrs, each moving 1KB CONTIGUOUS (vs 16 scattered 64B granules per
// instr in R10-R16) -> DRAM page locality. Compute reads frags from LDS.
//  - 4096 blocks x 256 thr; wave kq = K-quarter (7/6/6/6); 3 blocks/CU.
//  - staging: wave0 chunks 0-12, waves1-3: 12 each; __syncthreads drains.
//  - LDS addr (r16,kg,kt): r16*3136 + 16*kg + 128*kt (+64 for vb);
//    kt=24 vb clamps to row start (W=0 annihilates those slots).
//  - epilogue red[4][16][16] OVERLAYS the staging buffer (barrier-guarded).
// K-slot map (validated R9+): kt covers row bytes [128kt,128kt+128); every
// even float pair is a top/bottom pair of one patch; pads (jp>=784) W=0.

typedef __attribute__((ext_vector_type(8))) short short8;
typedef __attribute__((ext_vector_type(4))) float f32x4;

typedef __attribute__((address_space(1))) const void GAS;
typedef __attribute__((address_space(3))) void LAS;

__device__ __forceinline__ void gl_lds16(const void* g, void* l) {
    __builtin_amdgcn_global_load_lds((GAS*)g, (LAS*)l, 16, 0, 0);
}

// fast fp32 -> bf16 (round-half-up; validated R16, absmax 0.03125)
__device__ __forceinline__ short bf16h(float g) {
    return (short)((__float_as_uint(g) + 0x8000u) >> 16);
}

// ---- pre-kernel: bake W -> bf16 frags ws[kt][lane][e], 25 KB ----
__global__ void quanv_wprep_kernel(const float* __restrict__ Wm,
                                   uint32_t* __restrict__ ws) {
    const int idx = blockIdx.x * 256 + threadIdx.x;   // [0, 6400)
    if (idx >= 6400) return;
    const int kt  = idx >> 8;       // 0..24
    const int rem = idx & 255;
    const int l   = rem >> 2;       // lane 0..63
    const int d   = rem & 3;        // u32 -> e = 2d, 2d+1
    const int n   = l & 15;
    const int kg  = l >> 4;
    uint32_t outv = 0;
    if (n < 10) {
        uint32_t hv[2];
#pragma unroll
        for (int d2 = 0; d2 < 2; ++d2) {
            const int e  = 2 * d + d2;
            const int jp = 32 * kt + 4 * kg + 16 * (e >> 2) + 2 * ((e >> 1) & 1);
            float v = 0.f;
            if (jp < 784) {
                const int ri = jp / 28;          // image row
                const int pc = (jp % 28) >> 1;   // patch col
                const int pr = ri >> 1;          // patch row
                const int ho = ri & 1;           // 0=top pair, 1=bottom pair
                const int col = (pr * 14 + pc) * 4 + 2 * ho + (e & 1);
                v = Wm[n * 784 + col];
            }
            hv[d2] = (uint32_t)__bfloat16_as_ushort(__float2bfloat16(v));
        }
        outv = hv[0] | (hv[1] << 16);
    }
    ws[idx] = outv;
}

// ---- 8 features from two f32x4s (pairs (0,1),(2,3) each) ----
#define FEAT8(VA, VB, A) do {                                                 \
    { const float ce=__cosf((VA)[0]), co=__cosf((VA)[1]);                     \
      (A)[0] = bf16h(ce + (VA)[0]);                                           \
      (A)[1] = bf16h(fmaf(ce, co, (VA)[1])); }                                \
    { const float ce=__cosf((VA)[2]), co=__cosf((VA)[3]);                     \
      (A)[2] = bf16h(ce + (VA)[2]);                                           \
      (A)[3] = bf16h(fmaf(ce, co, (VA)[3])); }                                \
    { const float ce=__cosf((VB)[0]), co=__cosf((VB)[1]);                     \
      (A)[4] = bf16h(ce + (VB)[0]);                                           \
      (A)[5] = bf16h(fmaf(ce, co, (VB)[1])); }                                \
    { const float ce=__cosf((VB)[2]), co=__cosf((VB)[3]);                     \
      (A)[6] = bf16h(ce + (VB)[2]);                                           \
      (A)[7] = bf16h(fmaf(ce, co, (VB)[3])); }                                \
} while (0)

// ---- compute a K-window [KT0, KT0+N) from LDS ----
template <int KT0, int N>
__device__ __forceinline__ void quarter_lds(const char* __restrict__ lb,
                                            const char* __restrict__ wbp0,
                                            f32x4& acc) {
    short8 wf[N];
#pragma unroll
    for (int j = 0; j < N; ++j)
        wf[j] = *(const short8*)(wbp0 + (KT0 + j) * 1024);
#pragma unroll
    for (int j = 0; j < N; ++j) {
        const int kt = KT0 + j;
        const f32x4 va = *(const f32x4*)(lb + 128 * kt);
        const f32x4 vb = (kt == 24) ? *(const f32x4*)(lb)
                                    : *(const f32x4*)(lb + 128 * kt + 64);
        short8 a;
        FEAT8(va, vb, a);
        acc = __builtin_amdgcn_mfma_f32_16x16x32_bf16(a, wf[j], acc, 0, 0, 0);
    }
}

__global__ __launch_bounds__(256, 3)
void quanv_mfma12_kernel(const float* __restrict__ x,
                         const char* __restrict__ wsb,  // bf16 frags [25][64][8]
                         const float* __restrict__ bias,
                         float* __restrict__ out) {
    __shared__ char smraw[50176];   // 49 KB x-tile; epilogue red[] overlays

    const int t   = threadIdx.x;
    const int l   = t & 63;
    const int kq  = __builtin_amdgcn_readfirstlane(t >> 6);   // K-quarter 0..3
    const int r16 = l & 15;
    const int kg  = l >> 4;
    const int rowBase = blockIdx.x * 16;
    const char* gtile = (const char*)x + (size_t)rowBase * 3136; // contiguous 49KB

    // ---- stage: 49 chunks of 1KB contiguous; wave0: 0-12, w1-3: 12 each ----
    const int c0 = (kq == 0) ? 0 : 13 + (kq - 1) * 12;
    const int nc = (kq == 0) ? 13 : 12;
    for (int j = 0; j < nc; ++j) {
        const int c = c0 + j;
        const uint32_t lof = __builtin_amdgcn_readfirstlane((uint32_t)(c * 1024));
        gl_lds16(gtile + c * 1024 + l * 16, smraw + lof);
    }
    __syncthreads();   // drains vmcnt (staging + wf issue order safe) + barrier

    // ---- compute my K-quarter from LDS ----
    const char* lb   = smraw + r16 * 3136 + 16 * kg;
    const char* wbp0 = wsb + l * 16;
    f32x4 acc = {0.f, 0.f, 0.f, 0.f};
    if      (kq == 0) quarter_lds<0, 7>(lb, wbp0, acc);
    else if (kq == 1) quarter_lds<7, 6>(lb, wbp0, acc);
    else if (kq == 2) quarter_lds<13, 6>(lb, wbp0, acc);
    else              quarter_lds<19, 6>(lb, wbp0, acc);

    __syncthreads();   // all LDS reads done before red[] overlays the buffer

    // ---- deposit partials: red[kq][m][n] over the staging buffer ----
    float* red = (float*)smraw;    // [4][16][16]
#pragma unroll
    for (int j = 0; j < 4; ++j)
        red[(kq * 16 + 4 * kg + j) * 16 + r16] = acc[j];
    __syncthreads();

    // ---- epilogue: thread r (<16) owns row r; register log_softmax ----
    if (t < 16) {
        const int r = t;
        float lg[10];
#pragma unroll
        for (int n = 0; n < 10; ++n)
            lg[n] = red[(0 * 16 + r) * 16 + n] + red[(1 * 16 + r) * 16 + n]
                  + red[(2 * 16 + r) * 16 + n] + red[(3 * 16 + r) * 16 + n]
                  + bias[n];

        float mx = lg[0];
#pragma unroll
        for (int n = 1; n < 10; ++n) mx = fmaxf(mx, lg[n]);
        float sum = 0.f;
#pragma unroll
        for (int n = 0; n < 10; ++n) sum += __expf(lg[n] - mx);
        const float ls = __logf(sum) + mx;

        float* o = out + (size_t)(rowBase + r) * 10;   // 40B row, coalesced
#pragma unroll
        for (int n = 0; n < 10; n += 2)
            *(float2*)(o + n) = make_float2(lg[n] - ls, lg[n + 1] - ls);
    }
}

extern "C" void kernel_launch(void* const* d_in, const int* in_sizes, int n_in,
                              void* d_out, int out_size, void* d_ws, size_t ws_size,
                              hipStream_t stream) {
    const float* x    = (const float*)d_in[0];   // [65536, 784]
    const float* Wm   = (const float*)d_in[1];   // [10, 784]
    const float* bias = (const float*)d_in[2];   // [10]
    float* out        = (float*)d_out;           // [65536, 10]

    quanv_wprep_kernel<<<dim3(25), dim3(256), 0, stream>>>(
        Wm, (uint32_t*)d_ws);
    quanv_mfma12_kernel<<<dim3(4096), dim3(256), 0, stream>>>(
        x, (const char*)d_ws, bias, out);
}